// Round 1
// baseline (199.191 us; speedup 1.0000x reference)
//
#include <hip/hip_runtime.h>

#define WINSZ 2048
#define EMB   64

// ---------------------------------------------------------------------------
// Precompute 1: c[e] = W2[e] * (1 - sum_w W1[e,w]);  C = sum_e W2[e]*b1[e] + b2
// 64 blocks (one per e) x 256 threads.
// ---------------------------------------------------------------------------
__global__ __launch_bounds__(256) void nl_precompute_c(
    const float* __restrict__ W1, const float* __restrict__ b1,
    const float* __restrict__ W2, const float* __restrict__ b2,
    float* __restrict__ c, float* __restrict__ Cconst)
{
    const int e = blockIdx.x;
    const int t = threadIdx.x;

    float s = 0.0f;
    for (int w = t; w < WINSZ; w += 256) s += W1[e * WINSZ + w];

    // wave64 reduce
    for (int off = 32; off; off >>= 1) s += __shfl_down(s, off, 64);

    __shared__ float sm[4];
    const int lane = t & 63, wid = t >> 6;
    if (lane == 0) sm[wid] = s;
    __syncthreads();

    if (t == 0) {
        const float S1 = sm[0] + sm[1] + sm[2] + sm[3];
        c[e] = W2[e] * (1.0f - S1);
    }
    if (e == 0 && t == 0) {
        float acc = b2[0];
        #pragma unroll
        for (int i = 0; i < EMB; ++i) acc = fmaf(W2[i], b1[i], acc);
        *Cconst = acc;
    }
}

// ---------------------------------------------------------------------------
// Precompute 2: V[w*E + e] = W1[e*WIN + w] * W2[e]  (+ c[e] at w == WIN-1)
// 512 KB table; scattered W1 reads are negligible traffic.
// ---------------------------------------------------------------------------
__global__ __launch_bounds__(256) void nl_build_V(
    const float* __restrict__ W1, const float* __restrict__ W2,
    const float* __restrict__ c, float* __restrict__ V)
{
    const int i = blockIdx.x * 256 + threadIdx.x;   // 0 .. WIN*E-1
    if (i >= WINSZ * EMB) return;
    const int w = i >> 6;         // / EMB
    const int e = i & (EMB - 1);  // % EMB
    float v = W1[e * WINSZ + w] * W2[e];
    if (w == WINSZ - 1) v += c[e];
    V[i] = v;
}

// ---------------------------------------------------------------------------
// Main: out[b] = dot(x[b,:,:], V) + C.  One block per b; 256 threads; float4
// streaming loads of the contiguous 512 KB slice. V stays L2-resident.
// ---------------------------------------------------------------------------
__global__ __launch_bounds__(256) void nl_main(
    const float* __restrict__ x, const float* __restrict__ V,
    const float* __restrict__ Cconst, float* __restrict__ out)
{
    const int b = blockIdx.x;
    const int t = threadIdx.x;

    const float4* __restrict__ xp = (const float4*)(x + (size_t)b * (WINSZ * EMB));
    const float4* __restrict__ vp = (const float4*)V;

    float acc = 0.0f;
    constexpr int N4 = (WINSZ * EMB) / 4;   // 32768 float4 per batch row
    #pragma unroll 4
    for (int j = t; j < N4; j += 256) {
        const float4 xv = xp[j];
        const float4 vv = vp[j];
        acc = fmaf(xv.x, vv.x, acc);
        acc = fmaf(xv.y, vv.y, acc);
        acc = fmaf(xv.z, vv.z, acc);
        acc = fmaf(xv.w, vv.w, acc);
    }

    // wave64 reduce, then cross-wave via LDS
    for (int off = 32; off; off >>= 1) acc += __shfl_down(acc, off, 64);

    __shared__ float sm[4];
    const int lane = t & 63, wid = t >> 6;
    if (lane == 0) sm[wid] = acc;
    __syncthreads();

    if (t == 0) out[b] = sm[0] + sm[1] + sm[2] + sm[3] + *Cconst;
}

// ---------------------------------------------------------------------------
extern "C" void kernel_launch(void* const* d_in, const int* in_sizes, int n_in,
                              void* d_out, int out_size, void* d_ws, size_t ws_size,
                              hipStream_t stream)
{
    const float* x  = (const float*)d_in[0];   // [B, WIN, E]
    const float* W1 = (const float*)d_in[1];   // [E, WIN]
    const float* b1 = (const float*)d_in[2];   // [E]
    const float* W2 = (const float*)d_in[3];   // [E, 1]
    const float* b2 = (const float*)d_in[4];   // [1]
    float* out = (float*)d_out;                // [B] (B x 1 flattened)

    // Workspace layout: V[WIN*E] | c[E] | C[1]   -> ~525 KB
    float* V  = (float*)d_ws;
    float* c  = V + WINSZ * EMB;
    float* Cc = c + EMB;

    const int B = out_size;                    // 2048

    nl_precompute_c<<<EMB, 256, 0, stream>>>(W1, b1, W2, b2, c, Cc);
    nl_build_V<<<(WINSZ * EMB + 255) / 256, 256, 0, stream>>>(W1, W2, c, V);
    nl_main<<<B, 256, 0, stream>>>(x, V, Cc, out);
}

// Round 2
// 189.160 us; speedup vs baseline: 1.0530x; 1.0530x over previous
//
#include <hip/hip_runtime.h>

#define WINSZ 2048
#define EMB   64

typedef float f32x4 __attribute__((ext_vector_type(4)));

// ---------------------------------------------------------------------------
// Precompute 1: c[e] = W2[e] * (1 - sum_w W1[e,w]);  C = sum_e W2[e]*b1[e] + b2
// ---------------------------------------------------------------------------
__global__ __launch_bounds__(256) void nl_precompute_c(
    const float* __restrict__ W1, const float* __restrict__ b1,
    const float* __restrict__ W2, const float* __restrict__ b2,
    float* __restrict__ c, float* __restrict__ Cconst)
{
    const int e = blockIdx.x;
    const int t = threadIdx.x;

    float s = 0.0f;
    for (int w = t; w < WINSZ; w += 256) s += W1[e * WINSZ + w];

    for (int off = 32; off; off >>= 1) s += __shfl_down(s, off, 64);

    __shared__ float sm[4];
    const int lane = t & 63, wid = t >> 6;
    if (lane == 0) sm[wid] = s;
    __syncthreads();

    if (t == 0) {
        const float S1 = sm[0] + sm[1] + sm[2] + sm[3];
        c[e] = W2[e] * (1.0f - S1);
    }
    if (e == 0 && t == 0) {
        float acc = b2[0];
        #pragma unroll
        for (int i = 0; i < EMB; ++i) acc = fmaf(W2[i], b1[i], acc);
        *Cconst = acc;
    }
}

// ---------------------------------------------------------------------------
// Precompute 2: V[w*E + e] = W1[e*WIN + w] * W2[e]  (+ c[e] at w == WIN-1)
// ---------------------------------------------------------------------------
__global__ __launch_bounds__(256) void nl_build_V(
    const float* __restrict__ W1, const float* __restrict__ W2,
    const float* __restrict__ c, float* __restrict__ V)
{
    const int i = blockIdx.x * 256 + threadIdx.x;
    if (i >= WINSZ * EMB) return;
    const int w = i >> 6;
    const int e = i & (EMB - 1);
    float v = W1[e * WINSZ + w] * W2[e];
    if (w == WINSZ - 1) v += c[e];
    V[i] = v;
}

// ---------------------------------------------------------------------------
// Main: out[b] = dot(x[b,:,:], V) + C.
// x is streamed with NONTEMPORAL loads (zero reuse -> keep it out of L2 so
// the shared 512 KB V table stays L2-resident). 4 vector accumulators break
// the FMA dependency chain.
// ---------------------------------------------------------------------------
__global__ __launch_bounds__(256) void nl_main(
    const float* __restrict__ x, const float* __restrict__ V,
    const float* __restrict__ Cconst, float* __restrict__ out)
{
    const int b = blockIdx.x;
    const int t = threadIdx.x;

    const f32x4* __restrict__ xp = (const f32x4*)(x + (size_t)b * (WINSZ * EMB));
    const f32x4* __restrict__ vp = (const f32x4*)V;

    constexpr int N4 = (WINSZ * EMB) / 4;   // 32768 float4 per batch row

    f32x4 a0 = {0,0,0,0}, a1 = {0,0,0,0}, a2 = {0,0,0,0}, a3 = {0,0,0,0};

    // 32 outer iterations; each handles 4 wave-contiguous float4 chunks.
    for (int j0 = 0; j0 < N4; j0 += 256 * 4) {
        const int j = j0 + t;
        const f32x4 x0 = __builtin_nontemporal_load(xp + j);
        const f32x4 x1 = __builtin_nontemporal_load(xp + j + 256);
        const f32x4 x2 = __builtin_nontemporal_load(xp + j + 512);
        const f32x4 x3 = __builtin_nontemporal_load(xp + j + 768);
        const f32x4 v0 = vp[j];
        const f32x4 v1 = vp[j + 256];
        const f32x4 v2 = vp[j + 512];
        const f32x4 v3 = vp[j + 768];
        a0 += x0 * v0;
        a1 += x1 * v1;
        a2 += x2 * v2;
        a3 += x3 * v3;
    }

    const f32x4 av = (a0 + a1) + (a2 + a3);
    float acc = (av.x + av.y) + (av.z + av.w);

    for (int off = 32; off; off >>= 1) acc += __shfl_down(acc, off, 64);

    __shared__ float sm[4];
    const int lane = t & 63, wid = t >> 6;
    if (lane == 0) sm[wid] = acc;
    __syncthreads();

    if (t == 0) out[b] = sm[0] + sm[1] + sm[2] + sm[3] + *Cconst;
}

// ---------------------------------------------------------------------------
extern "C" void kernel_launch(void* const* d_in, const int* in_sizes, int n_in,
                              void* d_out, int out_size, void* d_ws, size_t ws_size,
                              hipStream_t stream)
{
    const float* x  = (const float*)d_in[0];   // [B, WIN, E]
    const float* W1 = (const float*)d_in[1];   // [E, WIN]
    const float* b1 = (const float*)d_in[2];   // [E]
    const float* W2 = (const float*)d_in[3];   // [E, 1]
    const float* b2 = (const float*)d_in[4];   // [1]
    float* out = (float*)d_out;                // [B]

    float* V  = (float*)d_ws;
    float* c  = V + WINSZ * EMB;
    float* Cc = c + EMB;

    const int B = out_size;                    // 2048

    nl_precompute_c<<<EMB, 256, 0, stream>>>(W1, b1, W2, b2, c, Cc);
    nl_build_V<<<(WINSZ * EMB + 255) / 256, 256, 0, stream>>>(W1, W2, c, V);
    nl_main<<<B, 256, 0, stream>>>(x, V, Cc, out);
}

// Round 3
// 169.839 us; speedup vs baseline: 1.1728x; 1.1138x over previous
//
#include <hip/hip_runtime.h>

#define WINSZ 2048
#define EMB   64

typedef float f32x4 __attribute__((ext_vector_type(4)));

// ---------------------------------------------------------------------------
// Fused precompute: one block per e (64 blocks).
//   S1[e] = sum_w W1[e,w]   (coalesced row read, values kept in registers)
//   V[w*E + e] = W1[e,w]*W2[e]  (+ W2[e]*(1-S1[e]) at w == WIN-1)
//   block 0 also writes Cconst = sum_e W2[e]*b1[e] + b2
// Scattered 4B V stores: 512 KB total through L2 — negligible.
// ---------------------------------------------------------------------------
__global__ __launch_bounds__(256) void nl_precompute(
    const float* __restrict__ W1, const float* __restrict__ b1,
    const float* __restrict__ W2, const float* __restrict__ b2,
    float* __restrict__ V, float* __restrict__ Cconst)
{
    const int e = blockIdx.x;
    const int t = threadIdx.x;

    float vals[WINSZ / 256];          // 8 values per thread, static-indexed
    float s = 0.0f;
    #pragma unroll
    for (int k = 0; k < WINSZ / 256; ++k) {
        const int w = t + k * 256;
        vals[k] = W1[e * WINSZ + w];
        s += vals[k];
    }

    for (int off = 32; off; off >>= 1) s += __shfl_down(s, off, 64);

    __shared__ float sm[4];
    const int lane = t & 63, wid = t >> 6;
    if (lane == 0) sm[wid] = s;
    __syncthreads();

    const float S1 = sm[0] + sm[1] + sm[2] + sm[3];
    const float w2 = W2[e];
    const float ce = w2 * (1.0f - S1);

    #pragma unroll
    for (int k = 0; k < WINSZ / 256; ++k) {
        const int w = t + k * 256;
        float v = vals[k] * w2;
        if (w == WINSZ - 1) v += ce;
        V[w * EMB + e] = v;
    }

    if (e == 0 && t == 0) {
        float acc = b2[0];
        #pragma unroll
        for (int i = 0; i < EMB; ++i) acc = fmaf(W2[i], b1[i], acc);
        *Cconst = acc;
    }
}

// ---------------------------------------------------------------------------
// Main: out[b] = dot(x[b,:,:], V) + C.  TWO batch rows per block (1024
// blocks): each V load from L2 feeds two FMAs, halving load-issue pressure
// per HBM byte. x is streamed nontemporal (zero reuse, keep V L2-resident).
// ---------------------------------------------------------------------------
__global__ __launch_bounds__(256) void nl_main(
    const float* __restrict__ x, const float* __restrict__ V,
    const float* __restrict__ Cconst, float* __restrict__ out)
{
    const int b0 = blockIdx.x * 2;
    const int t  = threadIdx.x;

    constexpr int N4 = (WINSZ * EMB) / 4;   // 32768 float4 per batch row

    const f32x4* __restrict__ xp0 = (const f32x4*)(x + (size_t)b0 * (WINSZ * EMB));
    const f32x4* __restrict__ xp1 = xp0 + N4;
    const f32x4* __restrict__ vp  = (const f32x4*)V;

    f32x4 a00 = {0,0,0,0}, a01 = {0,0,0,0};
    f32x4 a10 = {0,0,0,0}, a11 = {0,0,0,0};

    // 64 outer iterations; 4 x-loads + 2 V-loads + 4 vec-FMAs each.
    for (int j0 = 0; j0 < N4; j0 += 512) {
        const int j = j0 + t;
        const f32x4 xA0 = __builtin_nontemporal_load(xp0 + j);
        const f32x4 xA1 = __builtin_nontemporal_load(xp0 + j + 256);
        const f32x4 xB0 = __builtin_nontemporal_load(xp1 + j);
        const f32x4 xB1 = __builtin_nontemporal_load(xp1 + j + 256);
        const f32x4 v0  = vp[j];
        const f32x4 v1  = vp[j + 256];
        a00 += xA0 * v0;
        a01 += xA1 * v1;
        a10 += xB0 * v0;
        a11 += xB1 * v1;
    }

    const f32x4 aA = a00 + a01;
    const f32x4 aB = a10 + a11;
    float r0 = (aA.x + aA.y) + (aA.z + aA.w);
    float r1 = (aB.x + aB.y) + (aB.z + aB.w);

    for (int off = 32; off; off >>= 1) {
        r0 += __shfl_down(r0, off, 64);
        r1 += __shfl_down(r1, off, 64);
    }

    __shared__ float smA[4], smB[4];
    const int lane = t & 63, wid = t >> 6;
    if (lane == 0) { smA[wid] = r0; smB[wid] = r1; }
    __syncthreads();

    if (t == 0) {
        const float C = *Cconst;
        out[b0]     = smA[0] + smA[1] + smA[2] + smA[3] + C;
        out[b0 + 1] = smB[0] + smB[1] + smB[2] + smB[3] + C;
    }
}

// ---------------------------------------------------------------------------
extern "C" void kernel_launch(void* const* d_in, const int* in_sizes, int n_in,
                              void* d_out, int out_size, void* d_ws, size_t ws_size,
                              hipStream_t stream)
{
    const float* x  = (const float*)d_in[0];   // [B, WIN, E]
    const float* W1 = (const float*)d_in[1];   // [E, WIN]
    const float* b1 = (const float*)d_in[2];   // [E]
    const float* W2 = (const float*)d_in[3];   // [E, 1]
    const float* b2 = (const float*)d_in[4];   // [1]
    float* out = (float*)d_out;                // [B]

    float* V  = (float*)d_ws;                  // WIN*E floats
    float* Cc = V + WINSZ * EMB;

    const int B = out_size;                    // 2048

    nl_precompute<<<EMB, 256, 0, stream>>>(W1, b1, W2, b2, V, Cc);
    nl_main<<<B / 2, 256, 0, stream>>>(x, V, Cc, out);
}